// Round 1
// baseline (17616.879 us; speedup 1.0000x reference)
//
#include <hip/hip_runtime.h>
#include <hip/hip_cooperative_groups.h>

namespace cg = cooperative_groups;

#define N_  1024
#define T_  512
#define B_  128
#define NI_ 6
#define NO_ 2

// sqrt(2/alpha)*sigma = sqrt(20)*0.03
#define NOISE_SCALE 0.13416407864998738f
#define ALPHA_ 0.1f
#define GAMMA_ 0.1f

// Persistent cooperative kernel.
// Grid: 256 blocks = 128 row-groups x 2 col-groups. Block: 512 threads = 8 waves.
// Block tile: 8 rows x 64 batch columns. Split-K across the 8 waves (128 k each).
__global__ __launch_bounds__(512) void rnn_kernel(
    const float* __restrict__ u,      // (NI, T, B)
    const float* __restrict__ rn,     // (N, T, B) rec_noise
    const float* __restrict__ ino,    // (NI, T, B) inp_noise
    const float* __restrict__ Wrec,   // (N, N)
    const float* __restrict__ Winp,   // (N, NI)
    const float* __restrict__ Wout,   // (NO, N)
    const float* __restrict__ yinit,  // (N,)
    float* __restrict__ out,          // (NO, T, B) -- pre-zeroed, atomicAdd target
    float* __restrict__ sbuf)         // workspace: 2 * N * B floats (ping-pong state)
{
    cg::grid_group grid = cg::this_grid();

    __shared__ float lds[8 * 8 * 64];   // [wave][row][col] split-K partials; [row][col] reuse for s_new

    const int g    = blockIdx.x & 1;          // column group (0/1)
    const int rb   = blockIdx.x >> 1;         // row block (0..127)
    const int row0 = rb * 8;
    const int tid  = threadIdx.x;
    const int lane = tid & 63;
    const int wave = __builtin_amdgcn_readfirstlane(tid >> 6);  // 0..7, force SGPR
    const int bcol = g * 64 + lane;           // batch column (0..127)

    float* buf0 = sbuf;
    float* buf1 = sbuf + N_ * B_;

    // ---- Prologue: state 0 = broadcast(y_init); emit out[:,0,:] ----
    {
        const int n = row0 + wave;
        const float s0 = yinit[n];
        buf0[n * B_ + bcol] = s0;
        lds[wave * 64 + lane] = s0;
        __syncthreads();
        if (tid < NO_ * 64) {
            const int o = __builtin_amdgcn_readfirstlane(tid >> 6);
            const int c = tid & 63;
            float p = 0.f;
#pragma unroll
            for (int r2 = 0; r2 < 8; ++r2)
                p += Wout[o * N_ + row0 + r2] * lds[r2 * 64 + c];
            atomicAdd(&out[o * T_ * B_ + 0 * B_ + g * 64 + c], p);
        }
    }
    grid.sync();

    // ---- Main loop: T-1 Euler steps ----
    for (int t = 0; t < T_ - 1; ++t) {
        const float* scur = (t & 1) ? buf1 : buf0;
        float*       snxt = (t & 1) ? buf0 : buf1;

        const int k0 = wave * 128;
        float acc[8];
#pragma unroll
        for (int r = 0; r < 8; ++r) acc[r] = 0.f;

        for (int kk = 0; kk < 128; kk += 16) {
            float sv[16];
#pragma unroll
            for (int j = 0; j < 16; ++j)
                sv[j] = scur[(k0 + kk + j) * B_ + bcol];   // coalesced vector loads
#pragma unroll
            for (int r = 0; r < 8; ++r) {
                const float* wr = Wrec + (row0 + r) * N_ + k0 + kk;  // uniform -> s_load
#pragma unroll
                for (int j = 0; j < 16; ++j)
                    acc[r] = fmaf(wr[j], sv[j], acc[r]);
            }
        }

        // split-K partials -> LDS
#pragma unroll
        for (int r = 0; r < 8; ++r)
            lds[(wave * 8 + r) * 64 + lane] = acc[r];
        __syncthreads();

        // Reduce + pointwise. Thread -> (row = wave, col = lane).
        {
            float h = 0.f;
#pragma unroll
            for (int w = 0; w < 8; ++w)
                h += lds[(w * 8 + wave) * 64 + lane];

            const int n = row0 + wave;
#pragma unroll
            for (int j = 0; j < NI_; ++j) {
                const int idx = j * T_ * B_ + t * B_ + bcol;
                const float uv = u[idx] + NOISE_SCALE * ino[idx];
                h = fmaf(Winp[n * NI_ + j], uv, h);
            }

            const float s    = scur[n * B_ + bcol];
            const float relu = fmaxf(0.f, h);   // SLOPE = 1
            const float rhs  = -s + relu + NOISE_SCALE * rn[n * T_ * B_ + t * B_ + bcol]
                               - GAMMA_ * s * s * s;
            const float snew = fmaf(ALPHA_, rhs, s);

            snxt[n * B_ + bcol] = snew;

            // Note: lds[wave*64+lane] (w=0 region) was read only by THIS thread above -> safe overwrite.
            lds[wave * 64 + lane] = snew;
            __syncthreads();

            if (tid < NO_ * 64) {
                const int o = __builtin_amdgcn_readfirstlane(tid >> 6);
                const int c = tid & 63;
                float p = 0.f;
#pragma unroll
                for (int r2 = 0; r2 < 8; ++r2)
                    p += Wout[o * N_ + row0 + r2] * lds[r2 * 64 + c];
                atomicAdd(&out[o * T_ * B_ + (t + 1) * B_ + g * 64 + c], p);
            }
        }
        grid.sync();
    }
}

extern "C" void kernel_launch(void* const* d_in, const int* in_sizes, int n_in,
                              void* d_out, int out_size, void* d_ws, size_t ws_size,
                              hipStream_t stream) {
    const float* u    = (const float*)d_in[0];
    const float* rn   = (const float*)d_in[1];
    const float* ino  = (const float*)d_in[2];
    const float* Wrec = (const float*)d_in[3];
    const float* Winp = (const float*)d_in[4];
    const float* Wout = (const float*)d_in[5];
    const float* yin  = (const float*)d_in[6];
    float* out  = (float*)d_out;
    float* sbuf = (float*)d_ws;   // needs 2*N*B*4 = 1 MB

    hipMemsetAsync(d_out, 0, (size_t)out_size * sizeof(float), stream);

    void* args[] = {(void*)&u, (void*)&rn, (void*)&ino, (void*)&Wrec, (void*)&Winp,
                    (void*)&Wout, (void*)&yin, (void*)&out, (void*)&sbuf};
    hipLaunchCooperativeKernel((void*)rnn_kernel, dim3(256), dim3(512), args, 0, stream);
}